// Round 1
// baseline (340.842 us; speedup 1.0000x reference)
//
#include <hip/hip_runtime.h>
#include <math.h>

#define NB 2
#define NN 4096
#define FIN 128
#define FOUT 64
#define LALPHA 0.2f
#define NEGINF -9.0e15f
#define SENT -3.0e38f

// ws layout (float offsets)
#define WS_WH  0                        // NB*NN*FOUT
#define WS_S1  (NB*NN*FOUT)             // NB*NN
#define WS_S2  (WS_S1 + NB*NN)          // NB*NN
#define WS_M   (WS_S2 + NB*NN)          // NB*NN
#define WS_L   (WS_M + NB*NN)           // NB*NN   (atomic accum)
#define WS_ACC (WS_L + NB*NN)           // NB*NN*FOUT (atomic accum)

// K1: Wh = h @ W ; s1 = Wh@a1 ; s2 = Wh@a2. One wave per (b,row); lane = out feature.
__global__ __launch_bounds__(256) void k1_proj(const float* __restrict__ h,
                                               const float* __restrict__ W,
                                               const float* __restrict__ a,
                                               float* __restrict__ ws) {
    int gid  = blockIdx.x * 256 + threadIdx.x;
    int wid  = gid >> 6;            // 0 .. NB*NN-1
    int lane = threadIdx.x & 63;
    const float* hrow = h + (size_t)wid * FIN;
    float h0 = hrow[lane];
    float h1 = hrow[64 + lane];
    float acc = 0.f;
#pragma unroll
    for (int f = 0; f < 64; ++f) {
        float hf = __shfl(h0, f);
        acc = fmaf(hf, W[f * FOUT + lane], acc);
    }
#pragma unroll
    for (int f = 0; f < 64; ++f) {
        float hf = __shfl(h1, f);
        acc = fmaf(hf, W[(64 + f) * FOUT + lane], acc);
    }
    ws[WS_WH + (size_t)wid * FOUT + lane] = acc;
    float v1 = acc * a[lane];
    float v2 = acc * a[FOUT + lane];
#pragma unroll
    for (int off = 32; off; off >>= 1) {
        v1 += __shfl_xor(v1, off);
        v2 += __shfl_xor(v2, off);
    }
    if (lane == 0) { ws[WS_S1 + wid] = v1; ws[WS_S2 + wid] = v2; }
}

// K2: exact softmax row-max via monotonicity of leakyrelu:
// m[b][i] = lrelu(s1[b][i] + max_{j: adj[i][j]>0} s2[b][j]) ; NEGINF if row fully masked.
// Also zeroes the atomic accumulators (l, acc). One wave per row i (both batches).
__global__ __launch_bounds__(256) void k2_maxmask(const int* __restrict__ adj,
                                                  float* __restrict__ ws) {
    int gid  = blockIdx.x * 256 + threadIdx.x;
    int i    = gid >> 6;            // row 0..NN-1
    int lane = threadIdx.x & 63;
    const float* s2 = ws + WS_S2;
    float m0 = SENT, m1 = SENT;
    for (int j0 = 0; j0 < NN; j0 += 64) {
        int j = j0 + lane;
        int av = adj[(size_t)i * NN + j];
        float a0 = s2[j];
        float a1 = s2[NN + j];
        if (av > 0) { m0 = fmaxf(m0, a0); m1 = fmaxf(m1, a1); }
    }
#pragma unroll
    for (int off = 32; off; off >>= 1) {
        m0 = fmaxf(m0, __shfl_xor(m0, off));
        m1 = fmaxf(m1, __shfl_xor(m1, off));
    }
    if (lane == 0) {
        float s10 = ws[WS_S1 + i];
        float s11 = ws[WS_S1 + NN + i];
        float e0 = s10 + m0, e1 = s11 + m1;
        e0 = e0 >= 0.f ? e0 : LALPHA * e0;
        e1 = e1 >= 0.f ? e1 : LALPHA * e1;
        ws[WS_M + i]      = (m0 > -2.0e38f) ? e0 : NEGINF;
        ws[WS_M + NN + i] = (m1 > -2.0e38f) ? e1 : NEGINF;
        ws[WS_L + i] = 0.f;
        ws[WS_L + NN + i] = 0.f;
    }
    // zero acc for both batches (wave writes its row's 64 features)
    ws[WS_ACC + (size_t)i * FOUT + lane] = 0.f;
    ws[WS_ACC + (size_t)(NN + i) * FOUT + lane] = 0.f;
}

// K3: fused masked softmax + P@Wh. Block = 4 waves = 64 rows; 16 j-segments.
// Wave handles 16 rows; lane = (rowgroup rg = lane>>4, featgroup fg = lane&15),
// register tile 4 rows x 4 features x 2 batches. Exact m -> no rescaling;
// partial (l, acc) merged via atomicAdd.
__global__ __launch_bounds__(256) void k3_attn(const int* __restrict__ adj,
                                               float* __restrict__ ws) {
    __shared__ float ldsWh[NB][64][FOUT];   // 32 KB, staged per chunk
    __shared__ float pbuf[4][16][65];       // per-wave p, stride 65 = conflict-free

    const int tid  = threadIdx.x;
    const int w    = tid >> 6;
    const int lane = tid & 63;
    const int rg   = lane >> 4;
    const int fg   = lane & 15;
    const int itile = blockIdx.x & 63;
    const int seg   = blockIdx.x >> 6;      // 0..15
    const int i0    = itile * 64 + w * 16;  // wave's first row
    const int jbase = seg * (NN / 16);      // 256 j per segment

    const float* __restrict__ Wh = ws + WS_WH;
    const float* __restrict__ s1 = ws + WS_S1;
    const float* __restrict__ s2 = ws + WS_S2;
    const float* __restrict__ mv = ws + WS_M;

    float acc[NB][4][4];
    float lsum[NB][16];
#pragma unroll
    for (int b = 0; b < NB; ++b) {
#pragma unroll
        for (int r = 0; r < 4; ++r)
#pragma unroll
            for (int k = 0; k < 4; ++k) acc[b][r][k] = 0.f;
#pragma unroll
        for (int r = 0; r < 16; ++r) lsum[b][r] = 0.f;
    }

    for (int c = 0; c < 4; ++c) {           // 4 chunks of 64 j
        const int j0 = jbase + c * 64;
        __syncthreads();
        // stage Wh chunk for both batches: 2048 float4 granules, 8 per thread
        for (int g = tid; g < NB * 64 * 16; g += 256) {
            int b   = g >> 10;
            int rem = g & 1023;
            int jj  = rem >> 4;
            int f4  = (rem & 15) << 2;
            *(float4*)&ldsWh[b][jj][f4] =
                *(const float4*)&Wh[(size_t)(b * NN + j0 + jj) * FOUT + f4];
        }
        __syncthreads();

        int adjv[16];
#pragma unroll
        for (int b = 0; b < NB; ++b) {
            // ---- score phase: lane = jj, rows sequential ----
            float s2v = s2[b * NN + j0 + lane];
#pragma unroll
            for (int r = 0; r < 16; ++r) {
                const int i = i0 + r;
                if (b == 0) adjv[r] = adj[(size_t)i * NN + j0 + lane];
                float s1v = s1[b * NN + i];
                float mvl = mv[b * NN + i];
                float e = s1v + s2v;
                e = e >= 0.f ? e : LALPHA * e;
                float sc = adjv[r] > 0 ? e : NEGINF;
                float p = __expf(sc - mvl);   // exact max: p <= 1; masked -> 0
                pbuf[w][r][lane] = p;
                lsum[b][r] += p;
            }
            // ---- FMA phase: lane = (rg,fg) ----
#pragma unroll 4
            for (int jj = 0; jj < 64; ++jj) {
                float4 wv = *(const float4*)&ldsWh[b][jj][fg << 2];
#pragma unroll
                for (int r = 0; r < 4; ++r) {
                    float pv = pbuf[w][(rg << 2) + r][jj];
                    acc[b][r][0] = fmaf(pv, wv.x, acc[b][r][0]);
                    acc[b][r][1] = fmaf(pv, wv.y, acc[b][r][1]);
                    acc[b][r][2] = fmaf(pv, wv.z, acc[b][r][2]);
                    acc[b][r][3] = fmaf(pv, wv.w, acc[b][r][3]);
                }
            }
        }
    }

    // epilogue: merge partials
    float* lacc = ws + WS_L;
    float* aacc = ws + WS_ACC;
#pragma unroll
    for (int b = 0; b < NB; ++b)
#pragma unroll
        for (int r = 0; r < 16; ++r) {
            float v = lsum[b][r];
#pragma unroll
            for (int off = 32; off; off >>= 1) v += __shfl_xor(v, off);
            if (lane == 0) atomicAdd(&lacc[b * NN + i0 + r], v);
        }
#pragma unroll
    for (int b = 0; b < NB; ++b)
#pragma unroll
        for (int r = 0; r < 4; ++r) {
            float* dst = &aacc[(size_t)(b * NN + i0 + (rg << 2) + r) * FOUT + (fg << 2)];
            atomicAdd(dst + 0, acc[b][r][0]);
            atomicAdd(dst + 1, acc[b][r][1]);
            atomicAdd(dst + 2, acc[b][r][2]);
            atomicAdd(dst + 3, acc[b][r][3]);
        }
}

// K4: out = elu(acc / l)
__global__ __launch_bounds__(256) void k4_fin(const float* __restrict__ ws,
                                              float* __restrict__ out) {
    int idx = blockIdx.x * 256 + threadIdx.x;    // 0 .. NB*NN*FOUT-1
    int row = idx >> 6;
    float l = ws[WS_L + row];
    float v = ws[WS_ACC + idx] / l;
    out[idx] = v > 0.f ? v : (__expf(v) - 1.f);
}

extern "C" void kernel_launch(void* const* d_in, const int* in_sizes, int n_in,
                              void* d_out, int out_size, void* d_ws, size_t ws_size,
                              hipStream_t stream) {
    const float* h   = (const float*)d_in[0];
    const int*   adj = (const int*)d_in[1];
    const float* W   = (const float*)d_in[2];
    const float* a   = (const float*)d_in[3];
    float* ws  = (float*)d_ws;
    float* out = (float*)d_out;

    hipLaunchKernelGGL(k1_proj,    dim3(NB * NN / 4), dim3(256), 0, stream, h, W, a, ws);
    hipLaunchKernelGGL(k2_maxmask, dim3(NN / 4),      dim3(256), 0, stream, adj, ws);
    hipLaunchKernelGGL(k3_attn,    dim3(64 * 16),     dim3(256), 0, stream, adj, ws);
    hipLaunchKernelGGL(k4_fin,     dim3(NB * NN * FOUT / 256), dim3(256), 0, stream, ws, out);
}

// Round 2
// 169.041 us; speedup vs baseline: 2.0163x; 2.0163x over previous
//
#include <hip/hip_runtime.h>
#include <hip/hip_bf16.h>
#include <math.h>

#define NB 2
#define NN 4096
#define FIN 128
#define FOUT 64
#define LALPHA 0.2f

// ws float-offsets
#define WS_S1  0                          // NB*NN
#define WS_S2  (NB*NN)                    // NB*NN
#define WS_L   (2*NB*NN)                  // NB*NN   (atomic accum, zeroed in k1)
#define WS_ACC (3*NB*NN)                  // NB*NN*FOUT (atomic accum, zeroed in k1)
#define WS_WHT (3*NB*NN + NB*NN*FOUT)     // NB*FOUT*NN ushorts (bf16 Wh^T, [b][f][j])

typedef __attribute__((ext_vector_type(8))) short short8;
typedef __attribute__((ext_vector_type(4))) float f32x4;

static __device__ inline unsigned int pack2bf(float x, float y) {
    float2 f2; f2.x = x; f2.y = y;
    __hip_bfloat162 pp = __float22bfloat162_rn(f2);
    return *reinterpret_cast<unsigned int*>(&pp);
}

// K1: Wh = h@W ; s1 = Wh@a1 ; s2 = Wh@a2 ; WhT bf16 [b][f][j] ; zero l/acc.
// One wave per (b,row); lane = out feature. Block = 4 waves = 4 consecutive rows.
__global__ __launch_bounds__(256) void k1_proj(const float* __restrict__ h,
                                               const float* __restrict__ W,
                                               const float* __restrict__ a,
                                               float* __restrict__ ws) {
    __shared__ float tbuf[4][68];
    int gid  = blockIdx.x * 256 + threadIdx.x;
    int wid  = gid >> 6;            // 0 .. NB*NN-1
    int lane = threadIdx.x & 63;
    int w    = threadIdx.x >> 6;
    const float* hrow = h + (size_t)wid * FIN;
    float h0 = hrow[lane];
    float h1 = hrow[64 + lane];
    float acc = 0.f;
#pragma unroll
    for (int f = 0; f < 64; ++f) {
        float hf = __shfl(h0, f);
        acc = fmaf(hf, W[f * FOUT + lane], acc);
    }
#pragma unroll
    for (int f = 0; f < 64; ++f) {
        float hf = __shfl(h1, f);
        acc = fmaf(hf, W[(64 + f) * FOUT + lane], acc);
    }
    tbuf[w][lane] = acc;
    float v1 = acc * a[lane];
    float v2 = acc * a[FOUT + lane];
#pragma unroll
    for (int off = 32; off; off >>= 1) {
        v1 += __shfl_xor(v1, off);
        v2 += __shfl_xor(v2, off);
    }
    if (lane == 0) {
        ws[WS_S1 + wid] = v1;
        ws[WS_S2 + wid] = v2;
        ws[WS_L + wid]  = 0.f;
    }
    ws[WS_ACC + (size_t)wid * FOUT + lane] = 0.f;   // zero accumulator row
    __syncthreads();
    // transpose 4 rows x 64 f -> WhT bf16 [b][f][n0..n0+3]
    if (threadIdx.x < 64) {
        int f = threadIdx.x;
        int wid0 = blockIdx.x * 4;
        int b  = wid0 >> 12;         // wid0 / NN
        int n0 = wid0 & (NN - 1);
        unsigned short* whT = (unsigned short*)(ws + WS_WHT);
        uint2 pk;
        pk.x = pack2bf(tbuf[0][f], tbuf[1][f]);
        pk.y = pack2bf(tbuf[2][f], tbuf[3][f]);
        *(uint2*)&whT[(size_t)(b * FOUT + f) * NN + n0] = pk;
    }
}

// K3: fused masked softmax + P@Wh via MFMA.
// Block = 4 waves, 16 rows, both batches. Each wave owns a disjoint 256-j range
// (full 16x64 partial output + l column) -> no __syncthreads at all.
// grid = 256 i-tiles x 4 j-segments = 1024 blocks; partials merged by atomicAdd.
__global__ __launch_bounds__(256) void k3_attn(const int* __restrict__ adj,
                                               float* __restrict__ ws) {
    // wave-private A-buffers: [wave][batch][16 rows][128 j + 8 pad] bf16 (34816 B)
    __shared__ __align__(16) unsigned short pbuf[4][2][16][136];

    const int tid  = threadIdx.x;
    const int w    = tid >> 6;
    const int lane = tid & 63;
    const int col  = lane & 15;          // MFMA n / D col
    const int quad = lane >> 4;
    const int itile = blockIdx.x >> 2;
    const int seg   = blockIdx.x & 3;
    const int i0    = itile * 16;
    const int jw0   = seg * 1024 + w * 256;   // wave's j base

    const float* __restrict__ s1 = ws + WS_S1;
    const float* __restrict__ s2 = ws + WS_S2;
    const unsigned short* __restrict__ whT = (const unsigned short*)(ws + WS_WHT);

    float s1a[2][16];
#pragma unroll
    for (int b = 0; b < 2; ++b)
#pragma unroll
        for (int r = 0; r < 16; ++r) s1a[b][r] = s1[b * NN + i0 + r];

    short8 onesf;   // B fragment for the l column: B[k][0]=1, B[k][n>0]=0
    {
        short v = (col == 0) ? (short)0x3F80 : (short)0;
#pragma unroll
        for (int i = 0; i < 8; ++i) onesf[i] = v;
    }

    f32x4 accT[2][4];
    f32x4 accL[2];
#pragma unroll
    for (int b = 0; b < 2; ++b) {
#pragma unroll
        for (int nt = 0; nt < 4; ++nt) accT[b][nt] = (f32x4)0.f;
        accL[b] = (f32x4)0.f;
    }

#pragma unroll
    for (int c = 0; c < 2; ++c) {        // two 128-j chunks per wave
        const int jc0 = jw0 + c * 128;
        // ---- score phase: lane = j-pair (j = jc0 + 2*lane + {0,1}) ----
        float2 s20 = *(const float2*)&s2[jc0 + 2 * lane];
        float2 s21 = *(const float2*)&s2[NN + jc0 + 2 * lane];
#pragma unroll
        for (int r = 0; r < 16; ++r) {
            int2 av = *(const int2*)&adj[(size_t)(i0 + r) * NN + jc0 + 2 * lane];
            {
                float e0 = s1a[0][r] + s20.x; e0 = fmaxf(e0, LALPHA * e0);
                float e1 = s1a[0][r] + s20.y; e1 = fmaxf(e1, LALPHA * e1);
                float p0 = av.x > 0 ? __expf(e0) : 0.f;
                float p1 = av.y > 0 ? __expf(e1) : 0.f;
                *(unsigned int*)&pbuf[w][0][r][2 * lane] = pack2bf(p0, p1);
            }
            {
                float e0 = s1a[1][r] + s21.x; e0 = fmaxf(e0, LALPHA * e0);
                float e1 = s1a[1][r] + s21.y; e1 = fmaxf(e1, LALPHA * e1);
                float p0 = av.x > 0 ? __expf(e0) : 0.f;
                float p1 = av.y > 0 ? __expf(e1) : 0.f;
                *(unsigned int*)&pbuf[w][1][r][2 * lane] = pack2bf(p0, p1);
            }
        }
        // ---- MFMA phase (wave-coherent LDS RAW, compiler inserts lgkmcnt) ----
#pragma unroll
        for (int b = 0; b < 2; ++b) {
#pragma unroll
            for (int ks = 0; ks < 4; ++ks) {
                short8 afrag = *(const short8*)&pbuf[w][b][col][ks * 32 + quad * 8];
#pragma unroll
                for (int nt = 0; nt < 4; ++nt) {
                    const unsigned short* bp =
                        &whT[(size_t)(b * FOUT + nt * 16 + col) * NN + jc0 + ks * 32 + quad * 8];
                    short8 bfrag = *(const short8*)bp;
                    accT[b][nt] = __builtin_amdgcn_mfma_f32_16x16x32_bf16(
                        afrag, bfrag, accT[b][nt], 0, 0, 0);
                }
                accL[b] = __builtin_amdgcn_mfma_f32_16x16x32_bf16(
                    afrag, onesf, accL[b], 0, 0, 0);
            }
        }
    }

    // ---- epilogue: merge partials. D layout: col=lane&15, row=quad*4+reg ----
    float* lacc = ws + WS_L;
    float* aacc = ws + WS_ACC;
#pragma unroll
    for (int b = 0; b < 2; ++b) {
#pragma unroll
        for (int nt = 0; nt < 4; ++nt)
#pragma unroll
            for (int reg = 0; reg < 4; ++reg) {
                int row = quad * 4 + reg;
                atomicAdd(&aacc[(size_t)(b * NN + i0 + row) * FOUT + nt * 16 + col],
                          accT[b][nt][reg]);
            }
        if (col == 0) {
#pragma unroll
            for (int reg = 0; reg < 4; ++reg)
                atomicAdd(&lacc[b * NN + i0 + quad * 4 + reg], accL[b][reg]);
        }
    }
}

// K4: out = elu(acc / l)
__global__ __launch_bounds__(256) void k4_fin(const float* __restrict__ ws,
                                              float* __restrict__ out) {
    int idx = blockIdx.x * 256 + threadIdx.x;    // 0 .. NB*NN*FOUT-1
    int row = idx >> 6;
    float l = ws[WS_L + row];
    float v = ws[WS_ACC + idx] / l;
    out[idx] = v > 0.f ? v : (__expf(v) - 1.f);
}

extern "C" void kernel_launch(void* const* d_in, const int* in_sizes, int n_in,
                              void* d_out, int out_size, void* d_ws, size_t ws_size,
                              hipStream_t stream) {
    const float* h   = (const float*)d_in[0];
    const int*   adj = (const int*)d_in[1];
    const float* W   = (const float*)d_in[2];
    const float* a   = (const float*)d_in[3];
    float* ws  = (float*)d_ws;
    float* out = (float*)d_out;

    hipLaunchKernelGGL(k1_proj, dim3(NB * NN / 4), dim3(256), 0, stream, h, W, a, ws);
    hipLaunchKernelGGL(k3_attn, dim3(256 * 4),     dim3(256), 0, stream, adj, ws);
    hipLaunchKernelGGL(k4_fin,  dim3(NB * NN * FOUT / 256), dim3(256), 0, stream, ws, out);
}